// Round 13
// baseline (51.439 us; speedup 1.0000x reference)
//
#include <hip/hip_runtime.h>
#include <hip/hip_bf16.h>

typedef __attribute__((ext_vector_type(2)))  float f32x2;
typedef __attribute__((ext_vector_type(8)))  float f32x8;
typedef __attribute__((ext_vector_type(16))) float f32x16;
typedef __attribute__((ext_vector_type(2)))  __bf16 bf16x2;
typedef __attribute__((ext_vector_type(8)))  __bf16 bf16x8;
typedef __attribute__((ext_vector_type(4)))  unsigned int u32x4;

// f32x8 -> bf16x8, compiler-lowered (cold path).
static __device__ __forceinline__ bf16x8 cvt8(f32x8 v) {
    return __builtin_convertvector(v, bf16x8);
}
// f32 pair -> u32 of 2 bf16 (RNE), compiler-lowered packed cvt.
static __device__ __forceinline__ unsigned int pkcvt(f32x2 v) {
    return __builtin_bit_cast(unsigned int, __builtin_convertvector(v, bf16x2));
}
static __device__ __forceinline__ f32x2 max2(f32x2 v) {
    const f32x2 z = {0.f, 0.f};
    return __builtin_elementwise_max(v, z);
}

#define MFMA32(A, B, C) __builtin_amdgcn_mfma_f32_32x32x16_bf16((A), (B), (C), 0, 0, 0)

// kperm(h,i) = (i&3) + 8*(i>>2) + 4h : the 32x32 D-fragment row held in reg i
// of lane-group h — bijection on [0,16) over {h, i<8}. A2's K-order is permuted
// by it at init so D1 regs 0..7 pack directly into the next B-frag (no
// cross-lane ops; validated R11). Layer 3 consumes D2 regs 0..7 in packed-f32
// VALU with w3/b2 permuted identically; the lane-half partial sums are folded
// with __shfl_xor(.,32) (permlane32_swap same-operand form indicted in R12).
__global__ __launch_bounds__(256, 3) void mlp3_mfma32(
    const float* __restrict__ x,
    const float* __restrict__ W1, const float* __restrict__ b1,
    const float* __restrict__ W2, const float* __restrict__ b2,
    const float* __restrict__ W3, const float* __restrict__ b3,
    float* __restrict__ out, int n)
{
    const int tid  = (int)threadIdx.x;
    const int lane = tid & 63;
    const int row  = lane & 31;   // A-frag row / B col (point)
    const int h    = lane >> 5;   // K-half selector in frag layouts
    const int wv   = tid >> 6;

    // ---- weight fragments / constants (cold init, resident) ----
    bf16x8 a1[3], a2[3];
    f32x2  w3p[3][4], b2p[3][4];
    #pragma unroll
    for (int e = 0; e < 3; ++e) {
        f32x8 t = {0.f,0.f,0.f,0.f,0.f,0.f,0.f,0.f};
        if (h == 0 && row < 16) {
            t[0] = W1[e * 32 + row];        // k=0: W1[e][0][row]
            t[1] = W1[e * 32 + 16 + row];   // k=1: W1[e][1][row]
            t[2] = b1[e * 16 + row];        // k=2: b1 (x K-slot 2 = 1.0)
        }
        a1[e] = cvt8(t);
        f32x8 t2 = {0.f,0.f,0.f,0.f,0.f,0.f,0.f,0.f};
        if (row < 16) {
            #pragma unroll
            for (int i = 0; i < 8; ++i) {
                const int k = (i & 3) + 8 * (i >> 2) + 4 * h;   // kperm(h,i)
                t2[i] = W2[e * 256 + k * 16 + row];
            }
        }
        a2[e] = cvt8(t2);
        #pragma unroll
        for (int j = 0; j < 4; ++j) {
            const int i0 = 2 * j, i1 = 2 * j + 1;
            const int k0 = (i0 & 3) + 8 * (i0 >> 2) + 4 * h;
            const int k1 = (i1 & 3) + 8 * (i1 >> 2) + 4 * h;
            w3p[e][j] = (f32x2){ W3[e * 16 + k0], W3[e * 16 + k1] };
            b2p[e][j] = (f32x2){ b2[e * 16 + k0], b2[e * 16 + k1] };
        }
    }
    const float b30 = b3[0], b31 = b3[1], b32 = b3[2];
    f32x16 zz;
    #pragma unroll
    for (int r = 0; r < 16; ++r) zz[r] = 0.f;

    const int xoff = (wv * 32 + row) * 8;    // bytes into 1024B x-chunk
    const int ooff = (wv * 32 + row) * 12;   // bytes into 1536B out-chunk (lane<32)

    const int nblk   = n >> 7;               // 128 points per block-iter
    const int stride = (int)gridDim.x;

    int cb = (int)blockIdx.x;
    float2 xv = *reinterpret_cast<const float2*>((const char*)x + (size_t)cb * 1024 + xoff);

    while (true) {
        const int nb = cb + stride;
        const bool more = nb < nblk;
        float2 xn;
        if (more)                             // prefetch next iter's x
            xn = *reinterpret_cast<const float2*>((const char*)x + (size_t)nb * 1024 + xoff);

        // B1: k-slots {x0, x1, 1.0, 0...}; h=1 half garbage-safe (A1 zero there)
        u32x4 bu = { pkcvt((f32x2){xv.x, xv.y}), 0x3F80u, 0u, 0u };
        const bf16x8 bx = __builtin_bit_cast(bf16x8, bu);

        float ys[3];
        #pragma unroll
        for (int e = 0; e < 3; ++e) {
            f32x16 t1 = MFMA32(a1[e], bx, zz);
            u32x4 bhw;
            #pragma unroll
            for (int j = 0; j < 4; ++j)
                bhw[j] = pkcvt(max2((f32x2){ t1[2*j], t1[2*j+1] }));
            const bf16x8 bh = __builtin_bit_cast(bf16x8, bhw);

            f32x16 t2 = MFMA32(a2[e], bh, zz);
            f32x2 yp = {0.f, 0.f};
            #pragma unroll
            for (int j = 0; j < 4; ++j) {
                f32x2 q = max2((f32x2){ t2[2*j], t2[2*j+1] } + b2p[e][j]);
                yp += w3p[e][j] * q;          // packed fma
            }
            const float ysum = yp[0] + yp[1];            // this lane-half's 8 k's
            ys[e] = ysum + __shfl_xor(ysum, 32, 64);     // + other half's 8 k's
        }

        if (lane < 32) {
            *reinterpret_cast<float3*>((char*)out + (size_t)cb * 1536 + ooff) =
                make_float3(ys[0] + b30, ys[1] + b31, ys[2] + b32);
        }

        if (!more) break;
        cb = nb;
        xv = xn;
    }
}

extern "C" void kernel_launch(void* const* d_in, const int* in_sizes, int n_in,
                              void* d_out, int out_size, void* d_ws, size_t ws_size,
                              hipStream_t stream) {
    const float* x  = (const float*)d_in[0];
    const float* W1 = (const float*)d_in[1];
    const float* b1 = (const float*)d_in[2];
    const float* W2 = (const float*)d_in[3];
    const float* b2 = (const float*)d_in[4];
    const float* W3 = (const float*)d_in[5];
    const float* b3 = (const float*)d_in[6];
    float* out = (float*)d_out;
    (void)d_ws; (void)ws_size; (void)n_in; (void)out_size;

    const int n = in_sizes[0] / 2;   // 4194304 points (32768 * 128)
    const int block = 256;
    const int grid = 2048;           // 16 chunk-iterations per block

    mlp3_mfma32<<<grid, block, 0, stream>>>(x, W1, b1, W2, b2, W3, b3, out, n);
}